// Round 6
// baseline (2628.182 us; speedup 1.0000x reference)
//
#include <hip/hip_runtime.h>
#include <hip/hip_cooperative_groups.h>
#include <math.h>

namespace cg = cooperative_groups;

#define NLOC 100

typedef __attribute__((ext_vector_type(8))) _Float16 half8;
typedef __attribute__((ext_vector_type(4))) float f32x4;

// ---------------- workspace layout (float offsets) ----------------
#define H_OFF     0            // 51200 f32
#define QKV_OFF   51200        // 204800 f32 [100][2048]
#define OCAT_OFF  256000       // 51200 f32 slots = 100*1024 f16
#define FFN_OFF   307200       // 102400 f32 slots = 100*2048 f16
#define ACTA_OFF  409600       // 320064 f32 slots
#define ACTB_OFF  729664       // 320064
#define CWH_OFF   1049728      // 555776 f32 slots = 1111552 f16 conv wts L2..L10
#define CW1_OFF   1605504      // 320 f32: conv1 weights float4[8*9]
#define WQKVT_OFF 1605824      // 6291456 f32 slots (12*2048*512 f16)
#define WOT_OFF   7897280      // 3145728 f32 slots (12*512*1024 f16)
#define W1T_OFF   11043008     // 6291456
#define W2T_OFF   17334464     // 6291456
// end 23625920 floats = 94.5 MB

struct WPack { const float* w[9]; };   // conv layers 2..10
struct WTArgs { const float* src[6]; };

struct TParams {
    const unsigned short* wqkvt;
    const unsigned short* wot;
    const unsigned short* w1t;
    const unsigned short* w2t;
    const float* b1;
    const float* b2;
    float* h;
    float* qkv;
    unsigned short* ocat;
    unsigned short* ffn;
    float* out;
};

// ---------------- conv1 weight repack: [8][3][3][3] -> float4[oc*9+kk] ----------------
__global__ __launch_bounds__(256) void cw1repack(const float* __restrict__ w, float* __restrict__ w4)
{
    int idx = blockIdx.x*256 + threadIdx.x;   // 288 = 8*9*4
    if (idx >= 288) return;
    int c = idx & 3;
    int r = idx >> 2;
    int oc = r / 9, kk = r - oc*9;
    int ky = kk/3, kx = kk - ky*3;
    float v = 0.f;
    if (c < 3) v = w[((oc*3 + c)*3 + ky)*3 + kx];
    w4[idx] = v;
}

// ---------------- conv weights L2..L10 -> f16 Bt[oc][Kpad], k = kk*Cin + ic ----------------
__global__ __launch_bounds__(256) void cwrepack(WPack wp, unsigned short* __restrict__ dst)
{
    const int Cin[9]  = {8,16,32,32,64,64,128,128,256};
    const int shift[9]= {3,4,5,5,6,6,7,7,8};
    const int KS[9]   = {3,3,3,3,3,3,3,3,2};
    const int Kpad[9] = {96,160,288,288,576,576,1152,1152,1024};
    const int off[10] = {0,1536,6656,15872,34304,71168,144896,292352,587264,1111552};
    const int total = 1111552;
    for (int i = blockIdx.x*blockDim.x + threadIdx.x; i < total; i += gridDim.x*blockDim.x) {
        int l = 0;
        while (i >= off[l+1]) ++l;
        int rem = i - off[l];
        int kp = Kpad[l];
        int oc = rem / kp;
        int k  = rem - oc*kp;
        int ci = Cin[l];
        int ic = k & (ci - 1);
        int kk = k >> shift[l];
        int ks = KS[l], k2 = ks*ks;
        float v = 0.f;
        if (kk < k2) {
            int ky = kk / ks, kx = kk - ky*ks;
            v = wp.w[l][((oc*ci + ic)*ks + ky)*ks + kx];
        }
        _Float16 hv = (_Float16)v;
        dst[i] = __builtin_bit_cast(unsigned short, hv);
    }
}

// ---------------- merged transformer weight transpose fp32->f16, vectorized writes ----------
// tile = 64 K x 32 N. segments: 0=Wq 1=Wk 2=Wv (into wqkvt) 3=W1 4=W2 5=Wo
__global__ __launch_bounds__(256) void wtrans_all(WTArgs wa,
    unsigned short* __restrict__ wqkvt, unsigned short* __restrict__ w1t,
    unsigned short* __restrict__ w2t, unsigned short* __restrict__ wot)
{
    const int pre[7]  = {0, 1536, 3072, 6144, 12288, 18432, 21504};
    const int tXd[6]  = {4, 4, 8, 64, 16, 16};      // N/32
    const int Kd[6]   = {512, 512, 512, 512, 2048, 1024};
    const int Nd[6]   = {128, 128, 256, 2048, 512, 512};
    const int mpl[6]  = {4, 4, 4, 1, 1, 1};
    const int dls[6]  = {1048576, 1048576, 1048576, 1048576, 1048576, 524288};
    const int dbase[6]= {0, 262144, 524288, 0, 0, 0};
    __shared__ float tsh[64][33];
    int b = blockIdx.x;
    int seg = 0;
    while (b >= pre[seg+1]) ++seg;
    int lb = b - pre[seg];
    int K = Kd[seg], N = Nd[seg];
    int tX = tXd[seg];
    int tpm = tX * (K >> 6);
    int mz = lb / tpm;
    int r = lb - mz*tpm;
    int ty_ = r / tX;
    int tx_ = r - ty_*tX;
    int layer = mz / mpl[seg];
    int mi = mz - layer*mpl[seg];
    const float* s = wa.src[seg] + (size_t)mz * K * N;
    unsigned short* base = (seg < 3) ? wqkvt : (seg == 3 ? w1t : (seg == 4 ? w2t : wot));
    unsigned short* d = base + (size_t)layer*dls[seg] + dbase[seg] + (size_t)mi * N * K;
    int n0 = tx_*32, k0 = ty_*64;
    int lx = threadIdx.x & 31, ly = threadIdx.x >> 5;   // ly in [0,8)
    #pragma unroll
    for (int i = 0; i < 8; ++i) {
        int k = i*8 + ly;
        tsh[k][lx] = s[(size_t)(k0 + k)*N + n0 + lx];
    }
    __syncthreads();
    #pragma unroll
    for (int i = 0; i < 4; ++i) {
        int nn = i*8 + ly;
        _Float16 h0 = (_Float16)tsh[2*lx][nn];
        _Float16 h1 = (_Float16)tsh[2*lx+1][nn];
        unsigned int wd = (unsigned int)__builtin_bit_cast(unsigned short, h0)
                        | ((unsigned int)__builtin_bit_cast(unsigned short, h1) << 16);
        unsigned int* du = (unsigned int*)(d + (size_t)(n0 + nn)*K + k0);
        du[lx] = wd;
    }
}

// ---------------- conv1: thread per pixel, 8 ocs, reads x directly ----------------
__global__ __launch_bounds__(256) void conv1k(const float* __restrict__ x,
    const float4* __restrict__ w4, const float* __restrict__ bias, unsigned short* __restrict__ out)
{
    int idx = blockIdx.x*256 + threadIdx.x;   // 32400 = 100*324
    if (idx >= 32400) return;
    int p = idx / 324;
    int s = idx - p*324;
    int sy = s / 18, sx = s - sy*18;
    int pi = p/10, pj = p - pi*10;
    const float* xb = x + (pj*20 + sy)*200 + pi*20 + sx;
    float acc[8];
    #pragma unroll
    for (int o = 0; o < 8; ++o) acc[o] = bias[o];
    #pragma unroll
    for (int ky = 0; ky < 3; ++ky)
        #pragma unroll
        for (int kx = 0; kx < 3; ++kx) {
            float r = xb[ky*200 + kx];
            float g = xb[40000 + ky*200 + kx];
            float bch = xb[80000 + ky*200 + kx];
            #pragma unroll
            for (int o = 0; o < 8; ++o) {
                float4 wv = w4[o*9 + ky*3 + kx];
                acc[o] += r*wv.x + g*wv.y + bch*wv.z;
            }
        }
    unsigned short h8[8];
    #pragma unroll
    for (int o = 0; o < 8; ++o) {
        _Float16 hv = (_Float16)acc[o];   // no relu after conv1
        h8[o] = __builtin_bit_cast(unsigned short, hv);
    }
    *(uint4*)(out + (size_t)idx*8) = *(const uint4*)h8;
}

// ---------------- MFMA conv: wave per 16x16 tile, implicit im2col ----------------
template<int CIN, int COUT, int KS, int HIN, int WIN, int HOUT, int WOUT, int KPAD, int RELU, int LAST>
__global__ __launch_bounds__(256) void convM(const unsigned short* __restrict__ in,
    const unsigned short* __restrict__ wth, const float* __restrict__ bias,
    unsigned short* __restrict__ out, float* __restrict__ hout)
{
    constexpr int HW = HOUT*WOUT;
    constexpr int M = 100*HW;
    constexpr int MT = (M + 15)/16;
    constexpr int NT = COUT/16;
    int wave = threadIdx.x >> 6, lane = threadIdx.x & 63;
    int t = blockIdx.x*4 + wave;
    if (t >= MT*NT) return;
    int mt = t % MT, nt = t / MT;
    int mrow = lane & 15, quad = lane >> 4;
    int mg = mt*16 + mrow; if (mg >= M) mg = M - 1;
    int p = mg / HW, s = mg - p*HW;
    int sy = s / WOUT, sx = s - sy*WOUT;
    const unsigned short* ap = in + ((size_t)((p*HIN + sy)*WIN + sx))*CIN;
    const unsigned short* bp = wth + ((size_t)(nt*16 + mrow))*KPAD + quad*8;
    f32x4 acc = {0.f, 0.f, 0.f, 0.f};
    #pragma unroll
    for (int k0 = 0; k0 < KPAD; k0 += 32) {
        int k = k0 + quad*8;
        int kk = k / CIN; if (kk > KS*KS - 1) kk = KS*KS - 1;
        int ky = kk / KS, kx = kk - ky*KS;
        uint4 av = *(const uint4*)(ap + (ky*WIN + kx)*CIN + (k & (CIN-1)));
        uint4 bv = *(const uint4*)(bp + k0);
        acc = __builtin_amdgcn_mfma_f32_16x16x32_f16(
            __builtin_bit_cast(half8, av), __builtin_bit_cast(half8, bv), acc, 0, 0, 0);
    }
    int n = nt*16 + mrow;
    float bv = bias[n];
    #pragma unroll
    for (int r = 0; r < 4; ++r) {
        int m = mt*16 + quad*4 + r;
        if (m < M) {
            float v = acc[r] + bv;
            if (RELU) v = fmaxf(v, 0.f);
            if (LAST) {
                int pi = m / 10;
                float pos = 20.f * (float)pi;
                int dd = n & 255;
                float inv = powf(10000.f, (float)dd * (1.f/128.f));
                float ang = pos / inv;
                v += (n < 256) ? sinf(ang) : cosf(ang);
                hout[(size_t)m*512 + n] = v;
            } else {
                _Float16 hv = (_Float16)v;
                out[(size_t)m*COUT + n] = __builtin_bit_cast(unsigned short, hv);
            }
        }
    }
}

// ---------------- the whole transformer: one cooperative kernel ----------------
// grid = 256 blocks x 256 threads (1 block/CU, co-resident). 1024 wave-slots.
__global__ __launch_bounds__(256) void transformer_all(TParams P)
{
    cg::grid_group grid = cg::this_grid();
    __shared__ float qr[128];
    __shared__ float pbuf[100];
    __shared__ float red[2];

    int t = threadIdx.x;
    int wave = t >> 6, lane = t & 63;
    int gw = blockIdx.x*4 + wave;           // 0..1023
    int mrow = lane & 15, quad = lane >> 4;

    for (int n = 0; n < 12; ++n) {
        const unsigned short* Bq  = P.wqkvt + (size_t)n * 2048 * 512;
        const unsigned short* Bo  = P.wot   + (size_t)n * 512 * 1024;
        const unsigned short* Bf1 = P.w1t   + (size_t)n * 2048 * 512;
        const unsigned short* Bf2 = P.w2t   + (size_t)n * 512 * 2048;
        const float* b1l = P.b1 + (size_t)n * 2048;
        const float* b2l = P.b2 + (size_t)n * 512;

        // ---- Stage A: qkv[100x2048] = h @ Wqkv ; 896 tiles (128n x 7m) ----
        if (gw < 896) {
            int nt = gw & 127, mt = gw >> 7;
            int n0 = nt*16, m0 = mt*16;
            int arow = m0 + mrow; if (arow > 99) arow = 99;
            const float* ap = P.h + (size_t)arow*512 + quad*8;
            const unsigned short* bp = Bq + (size_t)(n0 + mrow)*512 + quad*8;
            f32x4 acc = {0.f,0.f,0.f,0.f};
            #pragma unroll 8
            for (int k = 0; k < 512; k += 32) {
                float4 f0 = *(const float4*)(ap + k);
                float4 f1 = *(const float4*)(ap + k + 4);
                half8 af;
                af[0]=(_Float16)f0.x; af[1]=(_Float16)f0.y; af[2]=(_Float16)f0.z; af[3]=(_Float16)f0.w;
                af[4]=(_Float16)f1.x; af[5]=(_Float16)f1.y; af[6]=(_Float16)f1.z; af[7]=(_Float16)f1.w;
                uint4 bu = *(const uint4*)(bp + k);
                acc = __builtin_amdgcn_mfma_f32_16x16x32_f16(
                    af, __builtin_bit_cast(half8, bu), acc, 0, 0, 0);
            }
            int nn = n0 + mrow;
            #pragma unroll
            for (int r = 0; r < 4; ++r) {
                int row = m0 + quad*4 + r;
                if (row < 100) P.qkv[(size_t)row*2048 + nn] = acc[r];
            }
        }
        grid.sync();

        // ---- Stage B: attention; items = (head, query row), 400 ----
        for (int item = blockIdx.x; item < 400; item += 256) {
            int hh = item / 100, nq = item - hh*100;
            if (t < 128) qr[t] = P.qkv[(size_t)nq*2048 + hh*128 + t];
            __syncthreads();
            float sv = 0.f;
            if (t < 100) {
                const float4* kp = (const float4*)(P.qkv + (size_t)t*2048 + 512 + hh*128);
                const float4* q4 = (const float4*)qr;
                float s0=0.f, s1=0.f, s2=0.f, s3=0.f;
                #pragma unroll 8
                for (int j = 0; j < 32; ++j) {
                    float4 a = q4[j], b = kp[j];
                    s0 += a.x*b.x; s1 += a.y*b.y; s2 += a.z*b.z; s3 += a.w*b.w;
                }
                sv = (s0+s1+s2+s3) * 0.1f;    // scale = 1/sqrt(N_LOC) quirk
                pbuf[t] = sv;
            }
            __syncthreads();
            if (t < 64) {
                float m = fmaxf(pbuf[t], (t+64 < 100) ? pbuf[t+64] : -1e30f);
                for (int o = 32; o > 0; o >>= 1) m = fmaxf(m, __shfl_down(m, o));
                if (t == 0) red[0] = m;
            }
            __syncthreads();
            float mx = red[0];
            if (t < 100) pbuf[t] = expf(sv - mx);
            __syncthreads();
            if (t < 64) {
                float s = pbuf[t] + ((t+64 < 100) ? pbuf[t+64] : 0.f);
                for (int o = 32; o > 0; o >>= 1) s += __shfl_down(s, o);
                if (t == 0) red[1] = s;
            }
            __syncthreads();
            float inv = 1.0f / red[1];
            const float* vp = P.qkv + 1024 + hh*256 + t;
            float acc = 0.f;
            #pragma unroll 4
            for (int m = 0; m < 100; ++m) acc += pbuf[m] * vp[(size_t)m*2048];
            _Float16 hv = (_Float16)(acc * inv);
            P.ocat[(size_t)nq*1024 + hh*256 + t] = __builtin_bit_cast(unsigned short, hv);
            __syncthreads();
        }
        grid.sync();

        // ---- Stage C: h += ocat @ Wo ; 896 = 32n x 7m x 4 ksplit (K=1024) ----
        if (gw < 896) {
            int kz = gw / 224;
            int rr = gw - kz*224;
            int nt = rr & 31, mt = rr >> 5;
            int n0 = nt*16, m0 = mt*16, k0 = kz*256;
            int arow = m0 + mrow; if (arow > 99) arow = 99;
            const unsigned short* ap = P.ocat + (size_t)arow*1024 + quad*8 + k0;
            const unsigned short* bp = Bo + (size_t)(n0 + mrow)*1024 + quad*8 + k0;
            f32x4 acc = {0.f,0.f,0.f,0.f};
            #pragma unroll
            for (int k = 0; k < 256; k += 32) {
                uint4 au = *(const uint4*)(ap + k);
                uint4 bu = *(const uint4*)(bp + k);
                acc = __builtin_amdgcn_mfma_f32_16x16x32_f16(
                    __builtin_bit_cast(half8, au), __builtin_bit_cast(half8, bu), acc, 0, 0, 0);
            }
            int nn = n0 + mrow;
            #pragma unroll
            for (int r2 = 0; r2 < 4; ++r2) {
                int row = m0 + quad*4 + r2;
                if (row < 100) atomicAdd(&P.h[(size_t)row*512 + nn], acc[r2]);
            }
        }
        grid.sync();

        // ---- Stage D: ffn = relu(h @ W1 + b1) -> f16 ; 896 tiles (128n x 7m) ----
        if (gw < 896) {
            int nt = gw & 127, mt = gw >> 7;
            int n0 = nt*16, m0 = mt*16;
            int arow = m0 + mrow; if (arow > 99) arow = 99;
            const float* ap = P.h + (size_t)arow*512 + quad*8;
            const unsigned short* bp = Bf1 + (size_t)(n0 + mrow)*512 + quad*8;
            f32x4 acc = {0.f,0.f,0.f,0.f};
            #pragma unroll 8
            for (int k = 0; k < 512; k += 32) {
                float4 f0 = *(const float4*)(ap + k);
                float4 f1 = *(const float4*)(ap + k + 4);
                half8 af;
                af[0]=(_Float16)f0.x; af[1]=(_Float16)f0.y; af[2]=(_Float16)f0.z; af[3]=(_Float16)f0.w;
                af[4]=(_Float16)f1.x; af[5]=(_Float16)f1.y; af[6]=(_Float16)f1.z; af[7]=(_Float16)f1.w;
                uint4 bu = *(const uint4*)(bp + k);
                acc = __builtin_amdgcn_mfma_f32_16x16x32_f16(
                    af, __builtin_bit_cast(half8, bu), acc, 0, 0, 0);
            }
            int nn = n0 + mrow;
            float bv = b1l[nn];
            #pragma unroll
            for (int r = 0; r < 4; ++r) {
                int row = m0 + quad*4 + r;
                if (row < 100) {
                    float v = fmaxf(acc[r] + bv, 0.f);
                    _Float16 hv = (_Float16)v;
                    P.ffn[(size_t)row*2048 + nn] = __builtin_bit_cast(unsigned short, hv);
                }
            }
        }
        grid.sync();

        // ---- Stage E: h += ffn @ W2 + b2 ; 896 = 32n x 7m x 4 ksplit (K=2048) ----
        if (gw < 896) {
            int kz = gw / 224;
            int rr = gw - kz*224;
            int nt = rr & 31, mt = rr >> 5;
            int n0 = nt*16, m0 = mt*16, k0 = kz*512;
            int arow = m0 + mrow; if (arow > 99) arow = 99;
            const unsigned short* ap = P.ffn + (size_t)arow*2048 + quad*8 + k0;
            const unsigned short* bp = Bf2 + (size_t)(n0 + mrow)*2048 + quad*8 + k0;
            f32x4 acc = {0.f,0.f,0.f,0.f};
            #pragma unroll 8
            for (int k = 0; k < 512; k += 32) {
                uint4 au = *(const uint4*)(ap + k);
                uint4 bu = *(const uint4*)(bp + k);
                acc = __builtin_amdgcn_mfma_f32_16x16x32_f16(
                    __builtin_bit_cast(half8, au), __builtin_bit_cast(half8, bu), acc, 0, 0, 0);
            }
            int nn = n0 + mrow;
            float bv = (kz == 0) ? b2l[nn] : 0.f;
            #pragma unroll
            for (int r2 = 0; r2 < 4; ++r2) {
                int row = m0 + quad*4 + r2;
                if (row < 100) atomicAdd(&P.h[(size_t)row*512 + nn], acc[r2] + bv);
            }
        }
        grid.sync();
    }
    // final copy h -> out
    for (int i = blockIdx.x*256 + t; i < 51200; i += 65536) P.out[i] = P.h[i];
}

// ---------------- launch ----------------
extern "C" void kernel_launch(void* const* d_in, const int* in_sizes, int n_in,
                              void* d_out, int out_size, void* d_ws, size_t ws_size,
                              hipStream_t stream)
{
    const float* x = (const float*)d_in[0];
    const float* cw1 = (const float*)d_in[1];
    const float* cb[10];
    WPack wpk;
    for (int i = 0; i < 10; ++i) cb[i] = (const float*)d_in[2 + 2*i];
    for (int i = 0; i < 9; ++i)  wpk.w[i] = (const float*)d_in[3 + 2*i];  // conv layers 2..10
    const float* Wq = (const float*)d_in[21];
    const float* Wk = (const float*)d_in[22];
    const float* Wv = (const float*)d_in[23];
    const float* Wo = (const float*)d_in[24];
    const float* W1 = (const float*)d_in[25];
    const float* b1 = (const float*)d_in[26];
    const float* W2 = (const float*)d_in[27];
    const float* b2 = (const float*)d_in[28];

    float* ws = (float*)d_ws;
    float* h   = ws + H_OFF;
    float* qkv = ws + QKV_OFF;
    unsigned short* ocat = (unsigned short*)(ws + OCAT_OFF);
    unsigned short* ffn  = (unsigned short*)(ws + FFN_OFF);
    unsigned short* aA   = (unsigned short*)(ws + ACTA_OFF);
    unsigned short* aB   = (unsigned short*)(ws + ACTB_OFF);
    unsigned short* cwh  = (unsigned short*)(ws + CWH_OFF);
    float* cw14 = ws + CW1_OFF;
    unsigned short* wqkvt = (unsigned short*)(ws + WQKVT_OFF);
    unsigned short* wot   = (unsigned short*)(ws + WOT_OFF);
    unsigned short* w1t   = (unsigned short*)(ws + W1T_OFF);
    unsigned short* w2t   = (unsigned short*)(ws + W2T_OFF);

    // weight prep
    cw1repack<<<2, 256, 0, stream>>>(cw1, cw14);
    cwrepack<<<2172, 256, 0, stream>>>(wpk, cwh);
    WTArgs wargs;
    wargs.src[0] = Wq; wargs.src[1] = Wk; wargs.src[2] = Wv;
    wargs.src[3] = W1; wargs.src[4] = W2; wargs.src[5] = Wo;
    wtrans_all<<<21504, 256, 0, stream>>>(wargs, wqkvt, w1t, w2t, wot);

    // conv stack
    conv1k<<<127, 256, 0, stream>>>(x, (const float4*)cw14, cb[0], aA);
    convM<8,  16, 3,18,18,16,16,  96,1,0><<<400, 256, 0, stream>>>(aA, cwh + 0,      cb[1], aB, nullptr);
    convM<16, 32, 3,16,16,14,14, 160,0,0><<<613, 256, 0, stream>>>(aB, cwh + 1536,   cb[2], aA, nullptr);
    convM<32, 32, 3,14,14,12,12, 288,1,0><<<450, 256, 0, stream>>>(aA, cwh + 6656,   cb[3], aB, nullptr);
    convM<32, 64, 3,12,12,10,10, 288,1,0><<<625, 256, 0, stream>>>(aB, cwh + 15872,  cb[4], aA, nullptr);
    convM<64, 64, 3,10,10, 8, 8, 576,1,0><<<400, 256, 0, stream>>>(aA, cwh + 34304,  cb[5], aB, nullptr);
    convM<64,128, 3, 8, 8, 6, 6, 576,1,0><<<450, 256, 0, stream>>>(aB, cwh + 71168,  cb[6], aA, nullptr);
    convM<128,128,3, 6, 6, 4, 4,1152,1,0><<<200, 256, 0, stream>>>(aA, cwh + 144896, cb[7], aB, nullptr);
    convM<128,256,3, 4, 4, 2, 2,1152,1,0><<<100, 256, 0, stream>>>(aB, cwh + 292352, cb[8], aA, nullptr);
    convM<256,512,2, 2, 2, 1, 1,1024,0,1><<<56,  256, 0, stream>>>(aA, cwh + 587264, cb[9], nullptr, h);

    // transformer: one cooperative kernel (60 dispatches -> 1)
    TParams P;
    P.wqkvt = wqkvt; P.wot = wot; P.w1t = w1t; P.w2t = w2t;
    P.b1 = b1; P.b2 = b2;
    P.h = h; P.qkv = qkv; P.ocat = ocat; P.ffn = ffn;
    P.out = (float*)d_out;
    void* kargs[] = { &P };
    hipLaunchCooperativeKernel((const void*)transformer_all, dim3(256), dim3(256),
                               kargs, 0, stream);
}